// Round 5
// baseline (174.803 us; speedup 1.0000x reference)
//
#include <hip/hip_runtime.h>

// Soft-DTW, B=16 x O=64 pairs, N=M=256, gamma=0.2, band=128.
// One wave per (b,o) pair; lane owns 4 contiguous rows; anti-diagonal sweep.
// LOG-domain DP in K-scaled units: Rk = K*R, K = log2(e)/gamma.
//   softmin_k(a,b,c) = mn - log2(1 + 2^(mn-md) + 2^(mn-mx))   (exp args <= 0)
//   Rk_new = K*cost + softmin_k;   invalid / border cells = BIGK sentinel.
// No overflow possible; 2^(-huge)=0 reproduces the reference's BIG semantics.
// LDS layout swizzled p(j)=((j&3)<<6)|(j>>2): per-cell reads are 8B-stride
// across lanes (2-way alias, free) instead of 32B-stride (16-way conflict).

constexpr int Bn = 16, Nn = 256, On = 64, Mn = 256;
constexpr float INVK  = 0.13862943611198906f;  // gamma*ln(2) = 1/K
constexpr float Kf    = 7.2134752044448170f;   // log2(e)/gamma
constexpr float LOG2E = 1.4426950408889634f;
constexpr float BIGK  = 1.0e9f;                // sentinel

__global__ __launch_bounds__(64)
void dtw_kernel(const float* __restrict__ x, const float* __restrict__ y,
                const float* __restrict__ bias, const float* __restrict__ wt,
                float* __restrict__ out) {
    const int pair = blockIdx.x;          // 0..1023
    const int o = pair & (On - 1);
    const int b = pair >> 6;
    const int lane = threadIdx.x;         // 0..63

    __shared__ float2 yw[Mn];             // (y+bias, K*exp(w)) at index p(j)

    const float bo = bias[o];
    float4 y4 = reinterpret_cast<const float4*>(y + o * Mn)[lane];
    float4 w4 = reinterpret_cast<const float4*>(wt + o * Mn)[lane];
    {
        float yv[4] = {y4.x, y4.y, y4.z, y4.w};
        float wv[4] = {w4.x, w4.y, w4.z, w4.w};
        #pragma unroll
        for (int q = 0; q < 4; ++q) {
            // j = 4*lane + q -> p(j) = (q<<6) | lane  (stride-8B store, no conflict)
            yw[(q << 6) | lane] = make_float2(yv[q] + bo,
                                              Kf * __builtin_amdgcn_exp2f(wv[q] * LOG2E));
        }
    }
    __syncthreads();

    float4 x4 = reinterpret_cast<const float4*>(x + b * Nn)[lane];
    float xv[4] = {x4.x, x4.y, x4.z, x4.w};

    // per-row validity window in d:  valid <=> dlo[r] <= d <= dlo[r]+span[r]
    int dlo[4], span[4], jj[4];
    #pragma unroll
    for (int r = 0; r < 4; ++r) {
        int i = lane * 4 + r;
        int lo = max(i, 2 * i - 128);          // j>=0  and  i-j<=128
        int hi = min(i + 255, 2 * i + 128);    // j<=255 and j-i<=128
        dlo[r]  = lo;
        span[r] = hi - lo;
        jj[r]   = 1 - i;                       // column j at d=1
    }

    // diagonal 0: Rk[0,0] = K*c00, everything else BIG
    float2 p0 = yw[0];
    float x0 = __shfl(xv[0], 0);
    float df0 = x0 - p0.x;
    float c00k = df0 * df0 * p0.y;

    float r1[4] = {BIGK, BIGK, BIGK, BIGK};   // diag d-1
    float r2[4] = {BIGK, BIGK, BIGK, BIGK};   // diag d-2
    if (lane == 0) r1[0] = c00k;

    const bool l0 = (lane == 0);
    float sh_prev = BIGK;    // shift(r2[3]) for the current step (== prev up_in)

    #pragma unroll 6
    for (int d = 1; d <= 510; ++d) {
        float up_in = __shfl_up(r1[3], 1);    // R[i-1, j]   (diag d-1)
        up_in = l0 ? BIGK : up_in;
        float dg_in = sh_prev;                // R[i-1, j-1] (diag d-2), reused shfl
        float rn[4];
        #pragma unroll
        for (int r = 0; r < 4; ++r) {
            float up = r ? r1[r - 1] : up_in;
            float dg = r ? r2[r - 1] : dg_in;
            float lf = r1[r];
            int jc = min(max(jj[r], 0), Mn - 1);          // v_med3-able clamp
            float2 p = yw[((jc & 3) << 6) | (jc >> 2)];   // swizzled, conflict-free
            float diff = xv[r] - p.x;
            float ck = diff * diff * p.y;                 // K*cost
            float mn = fminf(fminf(dg, up), lf);
            float mx = fmaxf(fmaxf(dg, up), lf);
            float md = __builtin_amdgcn_fmed3f(dg, up, lf);
            float S = 1.0f + __builtin_amdgcn_exp2f(mn - md)
                           + __builtin_amdgcn_exp2f(mn - mx);
            float v = ck + mn - __builtin_amdgcn_logf(S); // logf == log2 on HW
            bool valid = (unsigned)(d - dlo[r]) <= (unsigned)span[r];
            rn[r] = valid ? v : BIGK;
            jj[r] += 1;
        }
        #pragma unroll
        for (int r = 0; r < 4; ++r) { r2[r] = r1[r]; r1[r] = rn[r]; }
        sh_prev = up_in;
    }

    if (lane == 63) out[pair] = r1[3] * INVK;   // R[255,255]
}

extern "C" void kernel_launch(void* const* d_in, const int* in_sizes, int n_in,
                              void* d_out, int out_size, void* d_ws, size_t ws_size,
                              hipStream_t stream) {
    const float* x    = (const float*)d_in[0];   // [16,256]
    const float* y    = (const float*)d_in[1];   // [64,256]
    const float* bias = (const float*)d_in[2];   // [64,1]
    const float* wt   = (const float*)d_in[3];   // [64,256]
    float* out = (float*)d_out;                  // [16,64]
    dtw_kernel<<<Bn * On, 64, 0, stream>>>(x, y, bias, wt, out);
}

// Round 6
// 162.361 us; speedup vs baseline: 1.0766x; 1.0766x over previous
//
#include <hip/hip_runtime.h>

// Soft-DTW, B=16 x O=64 pairs, N=M=256, gamma=0.2, band=128.
// One wave per (b,o) pair; lane owns 4 contiguous rows; anti-diagonal sweep.
// LOG-domain DP in K-scaled units: Rk = K*R, K = log2(e)/gamma.
//   softmin_k(a,b,c) = mn - log2(1 + 2^(mn-md) + 2^(mn-mx))   (exp args <= 0)
// Validity folded into cost: ck = valid ? K*cost : BIGK  (dead cells stay ~1e9,
// weight 2^-1e9 = 0 exactly -> reference BIG semantics).
// LDS swizzle p(j)=((j&3)<<6)|(j>>2) addressed by a walking BYTE offset with
// periodic compile-time deltas (+512,+512,+512,-1528; phase=(d-r)&3 is
// lane-invariant) + one v_med3_i32 clamp -> 1 VALU of address math per cell.

constexpr int Bn = 16, Nn = 256, On = 64, Mn = 256;
constexpr float INVK  = 0.13862943611198906f;  // gamma*ln(2) = 1/K
constexpr float Kf    = 7.2134752044448170f;   // log2(e)/gamma
constexpr float LOG2E = 1.4426950408889634f;
constexpr float BIGK  = 1.0e9f;                // sentinel

__global__ __launch_bounds__(64)
void dtw_kernel(const float* __restrict__ x, const float* __restrict__ y,
                const float* __restrict__ bias, const float* __restrict__ wt,
                float* __restrict__ out) {
    const int pair = blockIdx.x;          // 0..1023
    const int o = pair & (On - 1);
    const int b = pair >> 6;
    const int lane = threadIdx.x;         // 0..63

    __shared__ float2 yw[Mn];             // (y+bias, K*exp(w)) at index p(j)

    const float bo = bias[o];
    float4 y4 = reinterpret_cast<const float4*>(y + o * Mn)[lane];
    float4 w4 = reinterpret_cast<const float4*>(wt + o * Mn)[lane];
    {
        float yv[4] = {y4.x, y4.y, y4.z, y4.w};
        float wv[4] = {w4.x, w4.y, w4.z, w4.w};
        #pragma unroll
        for (int q = 0; q < 4; ++q) {
            yw[(q << 6) | lane] = make_float2(yv[q] + bo,
                                              Kf * __builtin_amdgcn_exp2f(wv[q] * LOG2E));
        }
    }
    __syncthreads();

    float4 x4 = reinterpret_cast<const float4*>(x + b * Nn)[lane];
    float xv[4] = {x4.x, x4.y, x4.z, x4.w};

    // per-row: valid <=> 0 <= (d - lo) <= span;  uv = d - lo, incremented per diag
    int uv[4], span[4], jb[4];
    #pragma unroll
    for (int r = 0; r < 4; ++r) {
        int i = lane * 4 + r;
        int lo = max(i, 2 * i - 128);          // j>=0  and  i-j<=128
        int hi = min(i + 255, 2 * i + 128);    // j<=255 and j-i<=128
        span[r] = hi - lo;
        uv[r]   = 0 - lo;                      // becomes d-lo after the d'th ++
        int j0  = 1 - i;                       // column j at d=1
        jb[r]   = (j0 & 3) * 512 + (j0 >> 2) * 8;  // virtual swizzled byte offset
    }

    // diagonal 0: Rk[0,0] = K*c00, everything else BIG
    float2 p00 = yw[0];
    float x0 = __shfl(xv[0], 0);
    float df0 = x0 - p00.x;
    float c00k = df0 * df0 * p00.y;

    float r1[4] = {BIGK, BIGK, BIGK, BIGK};   // diag d-1
    float r2[4] = {BIGK, BIGK, BIGK, BIGK};   // diag d-2
    if (lane == 0) r1[0] = c00k;

    const bool l0 = (lane == 0);
    float sh_prev = BIGK;                 // shift(r2[3]) == previous up_in
    const char* ywb = reinterpret_cast<const char*>(yw);
    float rn[4];

    auto cell = [&](int r, float dg, float up, float lf, int delta) {
        uv[r] += 1;
        int ab = min(max(jb[r], 0), (Mn - 1) * 8);     // v_med3_i32 clamp
        float2 p = *reinterpret_cast<const float2*>(ywb + ab);
        jb[r] += delta;
        float diff = xv[r] - p.x;
        float ck = diff * diff * p.y;                  // K*cost
        bool valid = (unsigned)uv[r] <= (unsigned)span[r];
        ck = valid ? ck : BIGK;
        float mn = fminf(fminf(dg, up), lf);           // v_min3_f32
        float mx = fmaxf(fmaxf(dg, up), lf);           // v_max3_f32
        float md = __builtin_amdgcn_fmed3f(dg, up, lf);
        float S = 1.0f + __builtin_amdgcn_exp2f(mn - md)
                       + __builtin_amdgcn_exp2f(mn - mx);
        rn[r] = ck + mn - __builtin_amdgcn_logf(S);    // logf == log2 HW
    };

    // phase of cell r at slot t (d = 1 + 4g + t):  s = (1+t-r)&3; delta:
    //   s==3 -> -1528 else +512
    auto dstep = [&](int t) {
        float up_in = __shfl_up(r1[3], 1);             // R[i-1, j]
        up_in = l0 ? BIGK : up_in;
        float dg_in = sh_prev;                         // R[i-1, j-1]
        // r = 3,2,1,0: shfl result only needed by r=0 -> overlaps 3 cells
        cell(3, r2[2], r1[2], r1[3], (((1 + t - 3) & 3) == 3) ? -1528 : 512);
        cell(2, r2[1], r1[1], r1[2], (((1 + t - 2) & 3) == 3) ? -1528 : 512);
        cell(1, r2[0], r1[0], r1[1], (((1 + t - 1) & 3) == 3) ? -1528 : 512);
        cell(0, dg_in, up_in, r1[0], (((1 + t - 0) & 3) == 3) ? -1528 : 512);
        #pragma unroll
        for (int r = 0; r < 4; ++r) { r2[r] = r1[r]; r1[r] = rn[r]; }
        sh_prev = up_in;
    };

    // diagonals 1..510 = 127 groups of 4 + 2 tail (phases stay aligned: 509%4==1)
    for (int g = 0; g < 127; ++g) {
        dstep(0); dstep(1); dstep(2); dstep(3);
    }
    dstep(0); dstep(1);

    if (lane == 63) out[pair] = r1[3] * INVK;   // R[255,255]
}

extern "C" void kernel_launch(void* const* d_in, const int* in_sizes, int n_in,
                              void* d_out, int out_size, void* d_ws, size_t ws_size,
                              hipStream_t stream) {
    const float* x    = (const float*)d_in[0];   // [16,256]
    const float* y    = (const float*)d_in[1];   // [64,256]
    const float* bias = (const float*)d_in[2];   // [64,1]
    const float* wt   = (const float*)d_in[3];   // [64,256]
    float* out = (float*)d_out;                  // [16,64]
    dtw_kernel<<<Bn * On, 64, 0, stream>>>(x, y, bias, wt, out);
}

// Round 7
// 150.622 us; speedup vs baseline: 1.1605x; 1.0779x over previous
//
#include <hip/hip_runtime.h>

// Soft-DTW, B=16 x O=64 pairs, N=M=256, gamma=0.2, band=128.
// One wave per (b,o) pair. SLIDING 192-row window (3 rows/lane), window base
// jumps +32 rows at 64-diagonal epoch boundaries: b_e = max(0, 32e-64).
// Coverage proof (valid rows at diag d: [max(0,ceil((d-128)/2), d-255), 
// min(255, d, floor((d+128)/2))]) checked per epoch; rows outside [0,255] or
// outside the band are masked to BIGK, so boundary-realign garbage (lanes
// wrapping in ds_bpermute) only ever feeds masked cells.
// LOG-domain DP in K-scaled units: Rk = K*R, K = log2(e)/gamma.
//   softmin_k(a,b,c) = mn - log2(1 + 2^(mn-md) + 2^(mn-mx))   (exp args <= 0)
// Cell math bitwise-identical to the previous (absmax 0.0) kernel.

constexpr int Bn = 16, Nn = 256, On = 64, Mn = 256;
constexpr float INVK  = 0.13862943611198906f;  // gamma*ln(2) = 1/K
constexpr float Kf    = 7.2134752044448170f;   // log2(e)/gamma
constexpr float LOG2E = 1.4426950408889634f;
constexpr float BIGK  = 1.0e9f;                // sentinel

__global__ __launch_bounds__(64)
void dtw_kernel(const float* __restrict__ x, const float* __restrict__ y,
                const float* __restrict__ bias, const float* __restrict__ wt,
                float* __restrict__ out) {
    const int pair = blockIdx.x;          // 0..1023
    const int o = pair & (On - 1);
    const int b = pair >> 6;
    const int lane = threadIdx.x;         // 0..63

    __shared__ float lds[768];  // [0,256): y+bias  [256,512): K*exp(w)  [512,768): x

    const float bo = bias[o];
    float4 y4 = reinterpret_cast<const float4*>(y + o * Mn)[lane];
    float4 w4 = reinterpret_cast<const float4*>(wt + o * Mn)[lane];
    float4 xg = reinterpret_cast<const float4*>(x + b * Nn)[lane];
    {
        float4 yb = make_float4(y4.x + bo, y4.y + bo, y4.z + bo, y4.w + bo);
        float4 kw = make_float4(Kf * __builtin_amdgcn_exp2f(w4.x * LOG2E),
                                Kf * __builtin_amdgcn_exp2f(w4.y * LOG2E),
                                Kf * __builtin_amdgcn_exp2f(w4.z * LOG2E),
                                Kf * __builtin_amdgcn_exp2f(w4.w * LOG2E));
        *reinterpret_cast<float4*>(&lds[4 * lane])       = yb;
        *reinterpret_cast<float4*>(&lds[256 + 4 * lane]) = kw;
        *reinterpret_cast<float4*>(&lds[512 + 4 * lane]) = xg;
    }
    __syncthreads();

    // diagonal 0: Rk[0,0] = K*c00 (row 0 = lane 0 slot 0)
    float df0 = lds[512] - lds[0];
    float c00k = df0 * df0 * lds[256];

    const bool l0 = (lane == 0);
    float r1[3] = {l0 ? c00k : BIGK, BIGK, BIGK};  // diag d-1
    float r2[3] = {BIGK, BIGK, BIGK};              // diag d-2
    float sh_prev = BIGK;                          // shfl_up(r2[2]) for next diag

    const char* lb = reinterpret_cast<const char*>(lds);

    #pragma unroll 1
    for (int e = 0; e < 8; ++e) {
        const int bwin = (32 * e - 64) > 0 ? (32 * e - 64) : 0;
        const int d0 = 64 * e + 1;                 // first diagonal of epoch

        if (e >= 3) {
            // window shifts +32 rows: new[l',s'] = old[l,s], 3l+s = 3l'+s'+32
            float n10 = __shfl(r1[2], lane + 10);
            float n11 = __shfl(r1[0], lane + 11);
            float n12 = __shfl(r1[1], lane + 11);
            float n20 = __shfl(r2[2], lane + 10);
            float n21 = __shfl(r2[0], lane + 11);
            float n22 = __shfl(r2[1], lane + 11);
            r1[0] = n10; r1[1] = n11; r1[2] = n12;
            r2[0] = n20; r2[1] = n21; r2[2] = n22;
            float sp = __shfl_up(r2[2], 1);
            sh_prev = l0 ? BIGK : sp;
        }

        // per-slot setup: row i = bwin + 3*lane + s
        int uv[3], span[3], jb[3];
        float xv[3];
        #pragma unroll
        for (int s = 0; s < 3; ++s) {
            int i = bwin + 3 * lane + s;
            int ic = min(i, 255);
            xv[s] = lds[512 + ic];
            int lo = max(i, 2 * i - 128);          // j>=0  and  i-j<=128
            int hi = min(i + 255, 2 * i + 128);    // j<=255 and j-i<=128
            bool live = (i <= 255);
            lo = live ? lo : 1000000000;           // dead rows: never valid
            span[s] = live ? (hi - lo) : 0;
            uv[s] = (d0 - 1) - lo;                 // becomes d-lo after ++
            jb[s] = (d0 - i) * 4;                  // byte offset of column j
        }

        float rn[3];
        auto cell = [&](int s, float dg, float up, float lf) {
            uv[s] += 1;
            int ab = min(max(jb[s], 0), (Mn - 1) * 4);     // v_med3 clamp
            jb[s] += 4;
            float yj  = *reinterpret_cast<const float*>(lb + ab);
            float kwj = *reinterpret_cast<const float*>(lb + ab + 1024);
            float diff = xv[s] - yj;
            float ck = diff * diff * kwj;                  // K*cost
            bool valid = (unsigned)uv[s] <= (unsigned)span[s];
            ck = valid ? ck : BIGK;
            float mn = fminf(fminf(dg, up), lf);           // v_min3_f32
            float mx = fmaxf(fmaxf(dg, up), lf);           // v_max3_f32
            float md = __builtin_amdgcn_fmed3f(dg, up, lf);
            float S = 1.0f + __builtin_amdgcn_exp2f(mn - md)
                           + __builtin_amdgcn_exp2f(mn - mx);
            rn[s] = ck + mn - __builtin_amdgcn_logf(S);    // logf == log2 HW
        };

        const int steps = (e < 7) ? 64 : 62;       // epoch 7 ends at d=510
        #pragma unroll 4
        for (int k = 0; k < steps; ++k) {
            float up_in = __shfl_up(r1[2], 1);     // R[i-1, j]
            up_in = l0 ? BIGK : up_in;
            float dg_in = sh_prev;                 // R[i-1, j-1] (reused shfl)
            // slot order 2,1,0: next shfl source rn[2] ready earliest
            cell(2, r2[1], r1[1], r1[2]);
            cell(1, r2[0], r1[0], r1[1]);
            cell(0, dg_in, up_in, r1[0]);
            r2[0] = r1[0]; r2[1] = r1[1]; r2[2] = r1[2];
            r1[0] = rn[0]; r1[1] = rn[1]; r1[2] = rn[2];
            sh_prev = up_in;
        }
    }

    // R[255,255]: row 255 = 160 + 3*31 + 2 -> lane 31, slot 2, diag 510
    if (lane == 31) out[pair] = r1[2] * INVK;
}

extern "C" void kernel_launch(void* const* d_in, const int* in_sizes, int n_in,
                              void* d_out, int out_size, void* d_ws, size_t ws_size,
                              hipStream_t stream) {
    const float* x    = (const float*)d_in[0];   // [16,256]
    const float* y    = (const float*)d_in[1];   // [64,256]
    const float* bias = (const float*)d_in[2];   // [64,1]
    const float* wt   = (const float*)d_in[3];   // [64,256]
    float* out = (float*)d_out;                  // [16,64]
    dtw_kernel<<<Bn * On, 64, 0, stream>>>(x, y, bias, wt, out);
}

// Round 8
// 127.374 us; speedup vs baseline: 1.3724x; 1.1825x over previous
//
#include <hip/hip_runtime.h>

// Soft-DTW, B=16 x O=64 pairs, N=M=256, gamma=0.2, band=128.
// One wave per (b,o) pair. SLIDING 128-row window (2 rows/lane): rows
// [w, w+127], w advances +1 every 2 diagonals for d in [128,382] (phase B).
// Coverage: exact except ONE band-edge cell (j-i=128, row (d-128)/2) at each
// even d in [128,382]; its softmin weight vs surviving paths is < 2^-100
// -> exactly 0 in f32 (reference-identical results).
// LOG-domain DP in K-scaled units: Rk = K*R, K = log2(e)/gamma.
//   softmin_k(a,b,c) = mn - log2(1 + 2^(mn-md) + 2^(mn-mx))   (exp args <= 0)
// Cell math bit-identical to the previous absmax-0.0 kernel.
// LDS: padded tables y[768] (idx=j+256), kw[768], x[256]; pads kw=0 -> ck=0
// for virtual j (always masked invalid) -> no address clamp needed.

constexpr int Bn = 16, Nn = 256, On = 64, Mn = 256;
constexpr float INVK  = 0.13862943611198906f;  // gamma*ln(2) = 1/K
constexpr float Kf    = 7.2134752044448170f;   // log2(e)/gamma
constexpr float LOG2E = 1.4426950408889634f;
constexpr float BIGK  = 1.0e9f;                // sentinel

__global__ __launch_bounds__(64)
void dtw_kernel(const float* __restrict__ x, const float* __restrict__ y,
                const float* __restrict__ bias, const float* __restrict__ wt,
                float* __restrict__ out) {
    const int pair = blockIdx.x;          // 0..1023
    const int o = pair & (On - 1);
    const int b = pair >> 6;
    const int lane = threadIdx.x;         // 0..63

    // floats: y[768] @0 (idx=j+256), kw[768] @768, x[256] @1536
    __shared__ float lds[1792];
    float4* L4 = reinterpret_cast<float4*>(lds);

    const float bo = bias[o];
    float4 y4 = reinterpret_cast<const float4*>(y + o * Mn)[lane];
    float4 w4 = reinterpret_cast<const float4*>(wt + o * Mn)[lane];
    float4 xg = reinterpret_cast<const float4*>(x + b * Nn)[lane];
    {
        float4 z4 = make_float4(0.f, 0.f, 0.f, 0.f);
        L4[lane]       = z4;   // y pad low   (idx 0..255)
        L4[128 + lane] = z4;   // y pad high  (idx 512..767)
        L4[192 + lane] = z4;   // kw pad low
        L4[320 + lane] = z4;   // kw pad high
        L4[64 + lane]  = make_float4(y4.x + bo, y4.y + bo, y4.z + bo, y4.w + bo);
        L4[256 + lane] = make_float4(Kf * __builtin_amdgcn_exp2f(w4.x * LOG2E),
                                     Kf * __builtin_amdgcn_exp2f(w4.y * LOG2E),
                                     Kf * __builtin_amdgcn_exp2f(w4.z * LOG2E),
                                     Kf * __builtin_amdgcn_exp2f(w4.w * LOG2E));
        L4[384 + lane] = xg;
    }
    __syncthreads();

    const char* lb = reinterpret_cast<const char*>(lds);
    const bool l0  = (lane == 0);
    const bool l63 = (lane == 63);

    // rows: i0 = w + 2*lane, i1 = i0 + 1; start w = 0
    int i0 = 2 * lane, i1 = 2 * lane + 1;
    float xv0 = lds[1536 + i0];
    float xv1 = lds[1536 + i1];
    int jb0 = (257 - i0) * 4;             // byte addr of y[idx(j)] at d=1
    int jb1 = (257 - i1) * 4;
    int jminb0, spanb0, jminb1, spanb1;
    auto bounds = [&](int i, int& jminb, int& spanb) {
        int jmin = max(i - 128, 0);
        int jmax = min(i + 128, 255);
        jminb = jmin * 4 + 1024;
        spanb = (jmax - jmin) * 4;
    };
    bounds(i0, jminb0, spanb0);
    bounds(i1, jminb1, spanb1);
    int xaddr1 = (1536 + i1 + 1) * 4;     // byte addr of x[i1+1] for 1st shift

    // diagonal 0: Rk[0,0] = K*c00  (row 0 = lane0 slot0)
    float df0 = lds[1536] - lds[256];
    float c00k = df0 * df0 * lds[1024];

    float r1s0 = l0 ? c00k : BIGK, r1s1 = BIGK;   // diag d-1
    float r2s0 = BIGK,             r2s1 = BIGK;   // diag d-2
    float sh_prev = BIGK;                          // shfl_up(r2s1) masked

    auto cell = [&](int jb, int jminb, int spanb, float xv,
                    float dg, float up, float lf) -> float {
        float yj = *reinterpret_cast<const float*>(lb + jb);
        float kj = *reinterpret_cast<const float*>(lb + jb + 3072);
        float diff = xv - yj;
        float ck = diff * diff * kj;                   // K*cost (0 for pad j)
        bool valid = (unsigned)(jb - jminb) <= (unsigned)spanb;
        ck = valid ? ck : BIGK;
        float mn = fminf(fminf(dg, up), lf);           // v_min3_f32
        float mx = fmaxf(fmaxf(dg, up), lf);           // v_max3_f32
        float md = __builtin_amdgcn_fmed3f(dg, up, lf);
        float S = 1.0f + __builtin_amdgcn_exp2f(mn - md)
                       + __builtin_amdgcn_exp2f(mn - mx);
        return ck + mn - __builtin_amdgcn_logf(S);     // logf == log2 HW
    };

    auto step = [&]() {
        float up_in = __shfl_up(r1s1, 1);              // R[i-1, j]
        up_in = l0 ? BIGK : up_in;
        float dg_in = sh_prev;                         // R[i-1, j-1]
        // slot1 first: its output feeds next diag's shfl earliest
        float n1 = cell(jb1, jminb1, spanb1, xv1, r2s0, r1s0, r1s1);
        float n0 = cell(jb0, jminb0, spanb0, xv0, dg_in, up_in, r1s0);
        r2s0 = r1s0; r2s1 = r1s1; r1s0 = n0; r1s1 = n1;
        sh_prev = up_in;
        jb0 += 4; jb1 += 4;
    };

    auto shift = [&]() {   // window w -> w+1 (rows +1); new top row = BIG
        float a1 = __shfl_down(r1s0, 1);
        float a2 = __shfl_down(r2s0, 1);
        r1s0 = r1s1; r1s1 = l63 ? BIGK : a1;
        r2s0 = r2s1; r2s1 = l63 ? BIGK : a2;
        float sp = __shfl_up(r2s1, 1);
        sh_prev = l0 ? BIGK : sp;
        i0 += 1; i1 += 1;
        bounds(i0, jminb0, spanb0);
        bounds(i1, jminb1, spanb1);
        xv0 = xv1;
        xv1 = *reinterpret_cast<const float*>(lb + xaddr1);
        xaddr1 += 4;
        jb0 -= 4; jb1 -= 4;   // i+=1 cancels previous step's j advance
    };

    // Phase A: d = 1..127 (w = 0)
    #pragma unroll 4
    for (int k = 0; k < 127; ++k) step();
    // Phase B: pairs p=0..127: shift to w=p+1, diags d=128+2p, 129+2p
    #pragma unroll 1
    for (int p = 0; p < 128; ++p) { shift(); step(); step(); }
    // Phase C: d = 384..510 (w = 128)
    #pragma unroll 4
    for (int k = 0; k < 127; ++k) step();

    // R[255,255]: row 255 = 128 + 2*63 + 1 -> lane 63, slot 1
    if (l63) out[pair] = r1s1 * INVK;
}

extern "C" void kernel_launch(void* const* d_in, const int* in_sizes, int n_in,
                              void* d_out, int out_size, void* d_ws, size_t ws_size,
                              hipStream_t stream) {
    const float* x    = (const float*)d_in[0];   // [16,256]
    const float* y    = (const float*)d_in[1];   // [64,256]
    const float* bias = (const float*)d_in[2];   // [64,1]
    const float* wt   = (const float*)d_in[3];   // [64,256]
    float* out = (float*)d_out;                  // [16,64]
    dtw_kernel<<<Bn * On, 64, 0, stream>>>(x, y, bias, wt, out);
}

// Round 9
// 105.885 us; speedup vs baseline: 1.6509x; 1.2030x over previous
//
#include <hip/hip_runtime.h>

// Soft-DTW, B=16 x O=64 pairs, N=M=256, gamma=0.2, band=128.
// One wave per (b,o) pair. CIRCULAR 128-row window, 2 slots/lane:
// physical slot p = 2*lane+s permanently holds row i == p (mod 128).
// Window [w, w+127]; advancing w (every 2 diags, d in [128,383]) = rebirth
// ONE slot (set r1/r2=BIGK, jb-=512, xv=preloaded x[row+128]) under a
// per-lane mask -- no data movement, nothing on the r critical path.
// Neighbor exchange = uniform rotate ds_bpermute (lane-1 mod 64).
// Rebirth timing makes every computed cell band-legal (reborn row enters at
// i-j=128; bottom rows exit at j-i=127) -> NO per-cell validity check.
// j outside [0,255] reads zero-pads (ck=0), preserving the ~1e9 sentinel
// (drift <= 511*log2(3) << 1e9) == reference BIG semantics in f32.
// LOG-domain DP in K-scaled units: Rk = K*R, K = log2(e)/gamma.
//   softmin_k(a,b,c) = mn - log2(1 + 2^(mn-md) + 2^(mn-mx))   (exp args <= 0)
// Cell math bit-identical to the absmax-0.0 R8 kernel.

constexpr int Bn = 16, Nn = 256, On = 64, Mn = 256;
constexpr float INVK  = 0.13862943611198906f;  // gamma*ln(2) = 1/K
constexpr float Kf    = 7.2134752044448170f;   // log2(e)/gamma
constexpr float LOG2E = 1.4426950408889634f;
constexpr float BIGK  = 1.0e9f;                // sentinel

__global__ __launch_bounds__(64)
void dtw_kernel(const float* __restrict__ x, const float* __restrict__ y,
                const float* __restrict__ bias, const float* __restrict__ wt,
                float* __restrict__ out) {
    const int pair = blockIdx.x;          // 0..1023
    const int o = pair & (On - 1);
    const int b = pair >> 6;
    const int lane = threadIdx.x;         // 0..63

    // floats: Y[768] @0 (idx=j+256), KW[768] @768 (byte 3072), X[256] @1536 (byte 6144)
    __shared__ float lds[1792];
    float4* L4 = reinterpret_cast<float4*>(lds);

    const float bo = bias[o];
    float4 y4 = reinterpret_cast<const float4*>(y + o * Mn)[lane];
    float4 w4 = reinterpret_cast<const float4*>(wt + o * Mn)[lane];
    float4 xg = reinterpret_cast<const float4*>(x + b * Nn)[lane];
    {
        float4 z4 = make_float4(0.f, 0.f, 0.f, 0.f);
        L4[lane]        = z4;   // Y pad low
        L4[128 + lane]  = z4;   // Y pad high
        L4[192 + lane]  = z4;   // KW pad low
        L4[320 + lane]  = z4;   // KW pad high
        L4[64 + lane]   = make_float4(y4.x + bo, y4.y + bo, y4.z + bo, y4.w + bo);
        L4[256 + lane]  = make_float4(Kf * __builtin_amdgcn_exp2f(w4.x * LOG2E),
                                      Kf * __builtin_amdgcn_exp2f(w4.y * LOG2E),
                                      Kf * __builtin_amdgcn_exp2f(w4.z * LOG2E),
                                      Kf * __builtin_amdgcn_exp2f(w4.w * LOG2E));
        L4[384 + lane]  = xg;
    }
    __syncthreads();

    const char* lb = reinterpret_cast<const char*>(lds);
    const bool l0 = (lane == 0);
    const int rotaddr = ((lane + 63) & 63) << 2;   // bpermute: lane-1 mod 64

    // per-slot state (rows i0 = 2*lane, i1 = 2*lane+1 at w=0)
    const int i0 = 2 * lane;
    float xv0 = lds[1536 + i0];
    float xv1 = lds[1536 + i0 + 1];
    const float px0 = lds[1536 + i0 + 128];        // x for reborn row 2*lane+128
    const float px1 = lds[1536 + i0 + 129];        // x for reborn row 2*lane+129
    int jb0 = (257 - i0) * 4;                      // byte off of Y[j+256] at d=1
    int jb1 = (256 - i0) * 4;

    // diagonal 0: Rk[0,0] = K*c00
    float df0 = lds[1536] - lds[256];
    float c00k = df0 * df0 * lds[1024];

    float r1s0 = l0 ? c00k : BIGK, r1s1 = BIGK;    // diag d-1
    float r2s0 = BIGK,             r2s1 = BIGK;    // diag d-2
    float sh_prev = BIGK;                          // rotate(r1s1) of prev diag

    auto rot = [&](float v) -> float {
        return __int_as_float(__builtin_amdgcn_ds_bpermute(rotaddr, __float_as_int(v)));
    };

    auto cell = [&](int jb, float xv, float dg, float up, float lf) -> float {
        float yj = *reinterpret_cast<const float*>(lb + jb);
        float kj = *reinterpret_cast<const float*>(lb + jb + 3072);
        float diff = xv - yj;
        float ck = diff * diff * kj;                   // K*cost (0 on pads)
        float mn = fminf(fminf(dg, up), lf);           // v_min3_f32
        float mx = fmaxf(fmaxf(dg, up), lf);           // v_max3_f32
        float md = __builtin_amdgcn_fmed3f(dg, up, lf);
        float S = 1.0f + __builtin_amdgcn_exp2f(mn - md)
                       + __builtin_amdgcn_exp2f(mn - mx);
        return ck + mn - __builtin_amdgcn_logf(S);     // logf == log2 HW
    };

    auto stepB = [&]() {                               // no boundary mask needed
        float up_in = rot(r1s1);
        float n1 = cell(jb1, xv1, r2s0, r1s0, r1s1);
        float n0 = cell(jb0, xv0, sh_prev, up_in, r1s0);
        r2s0 = r1s0; r2s1 = r1s1; r1s0 = n0; r1s1 = n1;
        sh_prev = up_in; jb0 += 4; jb1 += 4;
    };

    auto stepAC = [&]() {                              // lane0 slot0 = window bottom
        float up_in = rot(r1s1);
        float up0 = l0 ? BIGK : up_in;
        float dg0 = l0 ? BIGK : sh_prev;
        float n1 = cell(jb1, xv1, r2s0, r1s0, r1s1);
        float n0 = cell(jb0, xv0, dg0, up0, r1s0);
        r2s0 = r1s0; r2s1 = r1s1; r1s0 = n0; r1s1 = n1;
        sh_prev = up_in; jb0 += 4; jb1 += 4;
    };

    // Phase A: d = 1..127 (window [0,127])
    #pragma unroll 4
    for (int k = 0; k < 127; ++k) stepAC();

    // Phase B: 64 iters x 4 diags (d = 128..383), 2 rebirths per iter
    for (int q = 0; q < 64; ++q) {
        bool rb = (lane == q);
        // advance p=2q: rebirth slot0 of lane q as row 2q+128
        r1s0 = rb ? BIGK : r1s0;  r2s0 = rb ? BIGK : r2s0;
        jb0  = rb ? (jb0 - 512) : jb0;
        xv0  = rb ? px0 : xv0;
        stepB(); stepB();
        // advance p=2q+1: rebirth slot1 of lane q as row 2q+129
        r1s1 = rb ? BIGK : r1s1;  r2s1 = rb ? BIGK : r2s1;
        jb1  = rb ? (jb1 - 512) : jb1;
        xv1  = rb ? px1 : xv1;
        stepB(); stepB();
    }

    // Phase C: d = 384..510 (window [128,255]; bottom row 128 at lane0 slot0)
    #pragma unroll 4
    for (int k = 0; k < 127; ++k) stepAC();

    // R[255,255]: row 255 at slot 127 -> lane 63, slot 1
    if (lane == 63) out[pair] = r1s1 * INVK;
}

extern "C" void kernel_launch(void* const* d_in, const int* in_sizes, int n_in,
                              void* d_out, int out_size, void* d_ws, size_t ws_size,
                              hipStream_t stream) {
    const float* x    = (const float*)d_in[0];   // [16,256]
    const float* y    = (const float*)d_in[1];   // [64,256]
    const float* bias = (const float*)d_in[2];   // [64,1]
    const float* wt   = (const float*)d_in[3];   // [64,256]
    float* out = (float*)d_out;                  // [16,64]
    dtw_kernel<<<Bn * On, 64, 0, stream>>>(x, y, bias, wt, out);
}

// Round 10
// 105.331 us; speedup vs baseline: 1.6596x; 1.0053x over previous
//
#include <hip/hip_runtime.h>

// Soft-DTW, B=16 x O=64 pairs, N=M=256, gamma=0.2, band=128.
// One wave per (b,o) pair. CIRCULAR 128-row window, 2 slots/lane (R9 dataflow,
// absmax 0.0 verified): slot p = 2*lane+s holds row i == p (mod 128); window
// advance = rebirth ONE slot (BIGK, jb -= 512, xv = preloaded) under lane mask.
// Neighbor exchange = ds_bpermute rotate (precomputed address).
// NO per-cell validity: rebirth timing makes computed cells band-legal; j
// outside [0,255] reads zero-pads (ck=0) preserving the ~1e9 sentinel.
// LOG-domain DP: Rk = K*R; softmin_k = mn - log2(1 + 2^(mn-md) + 2^(mn-mx)).
//
// R10 changes (scheduling only, dataflow identical to R9):
//  - #pragma unroll 1 on phase-B q-loop: R9's regression was the compiler
//    fully unrolling 64 x ~130-instr body (~65KB) -> I-cache thrash at
//    1 wave/SIMD (VALUBusy 52->28% with FEWER instructions). Keep bodies small.
//  - register prefetch of (y,kw) one diagonal ahead: ds_read ~120cyc latency
//    off the critical path (loads have a full diagonal of slack).

constexpr int Bn = 16, Nn = 256, On = 64, Mn = 256;
constexpr float INVK  = 0.13862943611198906f;  // gamma*ln(2) = 1/K
constexpr float Kf    = 7.2134752044448170f;   // log2(e)/gamma
constexpr float LOG2E = 1.4426950408889634f;
constexpr float BIGK  = 1.0e9f;                // sentinel

__global__ __launch_bounds__(64)
void dtw_kernel(const float* __restrict__ x, const float* __restrict__ y,
                const float* __restrict__ bias, const float* __restrict__ wt,
                float* __restrict__ out) {
    const int pair = blockIdx.x;          // 0..1023
    const int o = pair & (On - 1);
    const int b = pair >> 6;
    const int lane = threadIdx.x;         // 0..63

    // floats: Y[768] @0 (idx=j+256), KW[768] @768 (byte 3072), X[256] @1536
    __shared__ float lds[1792];
    float4* L4 = reinterpret_cast<float4*>(lds);

    const float bo = bias[o];
    float4 y4 = reinterpret_cast<const float4*>(y + o * Mn)[lane];
    float4 w4 = reinterpret_cast<const float4*>(wt + o * Mn)[lane];
    float4 xg = reinterpret_cast<const float4*>(x + b * Nn)[lane];
    {
        float4 z4 = make_float4(0.f, 0.f, 0.f, 0.f);
        L4[lane]        = z4;   // Y pad low
        L4[128 + lane]  = z4;   // Y pad high
        L4[192 + lane]  = z4;   // KW pad low
        L4[320 + lane]  = z4;   // KW pad high
        L4[64 + lane]   = make_float4(y4.x + bo, y4.y + bo, y4.z + bo, y4.w + bo);
        L4[256 + lane]  = make_float4(Kf * __builtin_amdgcn_exp2f(w4.x * LOG2E),
                                      Kf * __builtin_amdgcn_exp2f(w4.y * LOG2E),
                                      Kf * __builtin_amdgcn_exp2f(w4.z * LOG2E),
                                      Kf * __builtin_amdgcn_exp2f(w4.w * LOG2E));
        L4[384 + lane]  = xg;
    }
    __syncthreads();

    const char* lb = reinterpret_cast<const char*>(lds);
    const bool l0 = (lane == 0);
    const int rotaddr = ((lane + 63) & 63) << 2;   // bpermute: lane-1 mod 64

    // per-slot state (rows i0 = 2*lane, i1 = 2*lane+1 at w=0)
    const int i0 = 2 * lane;
    float xv0 = lds[1536 + i0];
    float xv1 = lds[1536 + i0 + 1];
    const float px0 = lds[1536 + i0 + 128];        // x for reborn row +128
    const float px1 = lds[1536 + i0 + 129];
    int jb0 = (257 - i0) * 4;                      // byte off of Y[j+256] at d=1
    int jb1 = (256 - i0) * 4;

    // diagonal 0: Rk[0,0] = K*c00
    float df0 = lds[1536] - lds[256];
    float c00k = df0 * df0 * lds[1024];

    float r1s0 = l0 ? c00k : BIGK, r1s1 = BIGK;    // diag d-1
    float r2s0 = BIGK,             r2s1 = BIGK;    // diag d-2
    float sh_prev = BIGK;                          // rot(r1s1) of prev diag

    // prefetched table values for the CURRENT diagonal
    float y0c = *reinterpret_cast<const float*>(lb + jb0);
    float k0c = *reinterpret_cast<const float*>(lb + jb0 + 3072);
    float y1c = *reinterpret_cast<const float*>(lb + jb1);
    float k1c = *reinterpret_cast<const float*>(lb + jb1 + 3072);

    auto rot = [&](float v) -> float {
        return __int_as_float(__builtin_amdgcn_ds_bpermute(rotaddr, __float_as_int(v)));
    };

    auto softmin3 = [&](float dg, float up, float lf) -> float {
        float mn = fminf(fminf(dg, up), lf);           // v_min3_f32
        float mx = fmaxf(fmaxf(dg, up), lf);           // v_max3_f32
        float md = __builtin_amdgcn_fmed3f(dg, up, lf);
        float S = 1.0f + __builtin_amdgcn_exp2f(mn - md)
                       + __builtin_amdgcn_exp2f(mn - mx);
        return mn - __builtin_amdgcn_logf(S);          // logf == log2 HW
    };

    auto stepB = [&]() {                               // no boundary mask
        float up_in = rot(r1s1);
        float d1 = xv1 - y1c;  float ck1 = d1 * d1 * k1c;
        float d0 = xv0 - y0c;  float ck0 = d0 * d0 * k0c;
        jb0 += 4; jb1 += 4;
        // prefetch next diagonal (full diag of slack before use)
        float ny0 = *reinterpret_cast<const float*>(lb + jb0);
        float nk0 = *reinterpret_cast<const float*>(lb + jb0 + 3072);
        float ny1 = *reinterpret_cast<const float*>(lb + jb1);
        float nk1 = *reinterpret_cast<const float*>(lb + jb1 + 3072);
        float n1 = ck1 + softmin3(r2s0, r1s0, r1s1);
        float n0 = ck0 + softmin3(sh_prev, up_in, r1s0);
        y0c = ny0; k0c = nk0; y1c = ny1; k1c = nk1;
        r2s0 = r1s0; r2s1 = r1s1; r1s0 = n0; r1s1 = n1;
        sh_prev = up_in;
    };

    auto stepAC = [&]() {                              // lane0 slot0 = window bottom
        float up_in = rot(r1s1);
        float up0 = l0 ? BIGK : up_in;
        float dg0 = l0 ? BIGK : sh_prev;
        float d1 = xv1 - y1c;  float ck1 = d1 * d1 * k1c;
        float d0 = xv0 - y0c;  float ck0 = d0 * d0 * k0c;
        jb0 += 4; jb1 += 4;
        float ny0 = *reinterpret_cast<const float*>(lb + jb0);
        float nk0 = *reinterpret_cast<const float*>(lb + jb0 + 3072);
        float ny1 = *reinterpret_cast<const float*>(lb + jb1);
        float nk1 = *reinterpret_cast<const float*>(lb + jb1 + 3072);
        float n1 = ck1 + softmin3(r2s0, r1s0, r1s1);
        float n0 = ck0 + softmin3(dg0, up0, r1s0);
        y0c = ny0; k0c = nk0; y1c = ny1; k1c = nk1;
        r2s0 = r1s0; r2s1 = r1s1; r1s0 = n0; r1s1 = n1;
        sh_prev = up_in;
    };

    // Phase A: d = 1..127 (window [0,127])
    #pragma unroll 2
    for (int k = 0; k < 127; ++k) stepAC();

    // Phase B: 64 iters x 4 diags (d = 128..383), 2 rebirths per iter.
    // unroll 1: keep body (~165 instr) I-cache resident (R9 lesson).
    #pragma unroll 1
    for (int q = 0; q < 64; ++q) {
        bool rb = (lane == q);
        // rebirth slot0 of lane q as row 2q+128
        r1s0 = rb ? BIGK : r1s0;  r2s0 = rb ? BIGK : r2s0;
        jb0  = rb ? (jb0 - 512) : jb0;
        xv0  = rb ? px0 : xv0;
        y0c = *reinterpret_cast<const float*>(lb + jb0);          // refresh
        k0c = *reinterpret_cast<const float*>(lb + jb0 + 3072);
        stepB(); stepB();
        // rebirth slot1 of lane q as row 2q+129
        r1s1 = rb ? BIGK : r1s1;  r2s1 = rb ? BIGK : r2s1;
        jb1  = rb ? (jb1 - 512) : jb1;
        xv1  = rb ? px1 : xv1;
        y1c = *reinterpret_cast<const float*>(lb + jb1);          // refresh
        k1c = *reinterpret_cast<const float*>(lb + jb1 + 3072);
        stepB(); stepB();
    }

    // Phase C: d = 384..510 (window [128,255])
    #pragma unroll 2
    for (int k = 0; k < 127; ++k) stepAC();

    // R[255,255]: row 255 at slot 127 -> lane 63, slot 1
    if (lane == 63) out[pair] = r1s1 * INVK;
}

extern "C" void kernel_launch(void* const* d_in, const int* in_sizes, int n_in,
                              void* d_out, int out_size, void* d_ws, size_t ws_size,
                              hipStream_t stream) {
    const float* x    = (const float*)d_in[0];   // [16,256]
    const float* y    = (const float*)d_in[1];   // [64,256]
    const float* bias = (const float*)d_in[2];   // [64,1]
    const float* wt   = (const float*)d_in[3];   // [64,256]
    float* out = (float*)d_out;                  // [16,64]
    dtw_kernel<<<Bn * On, 64, 0, stream>>>(x, y, bias, wt, out);
}

// Round 12
// 97.461 us; speedup vs baseline: 1.7936x; 1.0807x over previous
//
#include <hip/hip_runtime.h>

// Soft-DTW, B=16 x O=64 pairs, N=M=256, gamma=0.2, band=128.
// One wave per (b,o) pair. CIRCULAR 128-row window, 2 slots/lane (absmax-0.0
// R10 dataflow): slot p = 2*lane+s holds row i == p (mod 128); window advance
// = rebirth ONE slot (BIGK, jb -= 1024, xv = preloaded) under a lane mask.
// NO per-cell validity: rebirth timing keeps computed cells band-legal; j
// outside [0,255] reads zero-pads (ck=0) preserving the ~1e9 sentinel.
// LOG-domain DP: Rk = K*R; softmin_k = mn - log2(1 + 2^(mn-md) + 2^(mn-mx)).
//
// R12 = R11 with the DPP rotate direction FIXED:
//   wave_ror:1 (0x13C): dest lane i <- src lane (i-1)&63  (lane0 <- lane63),
//   identical to the R10 bpermute mapping. R11's wave_rol:1 (0x134) was the
//   reverse direction (dest i <- src i+1) -> wrong up/dg operands -> absmax 108.
//   (Convention anchor: row_shr:1 = dest i <- src i-1, the scan idiom.)

constexpr int Bn = 16, Nn = 256, On = 64, Mn = 256;
constexpr float INVK  = 0.13862943611198906f;  // gamma*ln(2) = 1/K
constexpr float Kf    = 7.2134752044448170f;   // log2(e)/gamma
constexpr float LOG2E = 1.4426950408889634f;
constexpr float BIGK  = 1.0e9f;                // sentinel

__device__ __forceinline__ float rot1(float v) {   // lane l <- lane (l-1)&63
    return __int_as_float(__builtin_amdgcn_update_dpp(
        __float_as_int(v), __float_as_int(v), 0x13C /*wave_ror:1*/, 0xF, 0xF, true));
}

__global__ __launch_bounds__(64)
void dtw_kernel(const float* __restrict__ x, const float* __restrict__ y,
                const float* __restrict__ bias, const float* __restrict__ wt,
                float* __restrict__ out) {
    const int pair = blockIdx.x;          // 0..1023
    const int o = pair & (On - 1);
    const int b = pair >> 6;
    const int lane = threadIdx.x;         // 0..63

    // YW[768] float2 @byte0 (idx=j+256; pads idx<256,>=512 zero), X[256] @byte6144
    __shared__ float lds[1792];
    float4* L4 = reinterpret_cast<float4*>(lds);

    const float bo = bias[o];
    float4 y4 = reinterpret_cast<const float4*>(y + o * Mn)[lane];
    float4 w4 = reinterpret_cast<const float4*>(wt + o * Mn)[lane];
    float4 xg = reinterpret_cast<const float4*>(x + b * Nn)[lane];
    {
        float4 z4 = make_float4(0.f, 0.f, 0.f, 0.f);
        L4[lane]        = z4;   // YW pad low  (idx 0..127)
        L4[64 + lane]   = z4;   // YW pad low  (idx 128..255)
        L4[256 + lane]  = z4;   // YW pad high (idx 512..639)
        L4[320 + lane]  = z4;   // YW pad high (idx 640..767)
        float k0 = Kf * __builtin_amdgcn_exp2f(w4.x * LOG2E);
        float k1 = Kf * __builtin_amdgcn_exp2f(w4.y * LOG2E);
        float k2 = Kf * __builtin_amdgcn_exp2f(w4.z * LOG2E);
        float k3 = Kf * __builtin_amdgcn_exp2f(w4.w * LOG2E);
        // YW[256+4l+q] = (y[q]+bo, k[q]) -> two float4 stores
        L4[128 + 2 * lane]     = make_float4(y4.x + bo, k0, y4.y + bo, k1);
        L4[128 + 2 * lane + 1] = make_float4(y4.z + bo, k2, y4.w + bo, k3);
        L4[384 + lane]         = xg;     // X
    }
    __syncthreads();

    const char* lb = reinterpret_cast<const char*>(lds);
    const bool l0 = (lane == 0);

    // per-slot state (rows i0 = 2*lane, i1 = 2*lane+1 at w=0)
    const int i0 = 2 * lane;
    float xv0 = lds[1536 + i0];
    float xv1 = lds[1536 + i0 + 1];
    const float px0 = lds[1536 + i0 + 128];        // x for reborn row +128
    const float px1 = lds[1536 + i0 + 129];
    int jb0 = (257 - i0) * 8;                      // byte off of YW[j+256] at d=1
    int jb1 = (256 - i0) * 8;

    // diagonal 0: Rk[0,0] = K*c00   (YW[256] at byte 2048, X[0] at byte 6144)
    float2 pc00 = *reinterpret_cast<const float2*>(lb + 2048);
    float df0 = lds[1536] - pc00.x;
    float c00k = df0 * df0 * pc00.y;

    float r1s0 = l0 ? c00k : BIGK, r1s1 = BIGK;    // diag d-1
    float r2s0 = BIGK,             r2s1 = BIGK;    // diag d-2
    float sh_prev = BIGK;                          // rot(r1s1) of prev diag

    // prefetched table float2s for the CURRENT diagonal
    float2 p0c = *reinterpret_cast<const float2*>(lb + jb0);
    float2 p1c = *reinterpret_cast<const float2*>(lb + jb1);

    auto softmin3 = [&](float dg, float up, float lf) -> float {
        float mn = fminf(fminf(dg, up), lf);           // v_min3_f32
        float mx = fmaxf(fmaxf(dg, up), lf);           // v_max3_f32
        float md = __builtin_amdgcn_fmed3f(dg, up, lf);
        float S = 1.0f + __builtin_amdgcn_exp2f(mn - md)
                       + __builtin_amdgcn_exp2f(mn - mx);
        return mn - __builtin_amdgcn_logf(S);          // logf == log2 HW
    };

    auto stepB = [&]() {                               // circular, no mask
        float up_in = rot1(r1s1);
        float d1 = xv1 - p1c.x;  float ck1 = d1 * d1 * p1c.y;
        float d0 = xv0 - p0c.x;  float ck0 = d0 * d0 * p0c.y;
        jb0 += 8; jb1 += 8;
        float2 np0 = *reinterpret_cast<const float2*>(lb + jb0);
        float2 np1 = *reinterpret_cast<const float2*>(lb + jb1);
        float n1 = ck1 + softmin3(r2s0, r1s0, r1s1);
        float n0 = ck0 + softmin3(sh_prev, up_in, r1s0);
        p0c = np0; p1c = np1;
        r2s0 = r1s0; r2s1 = r1s1; r1s0 = n0; r1s1 = n1;
        sh_prev = up_in;
    };

    auto stepAC = [&]() {                              // lane0 slot0 = window bottom
        float up_in = rot1(r1s1);
        float up0 = l0 ? BIGK : up_in;
        float dg0 = l0 ? BIGK : sh_prev;
        float d1 = xv1 - p1c.x;  float ck1 = d1 * d1 * p1c.y;
        float d0 = xv0 - p0c.x;  float ck0 = d0 * d0 * p0c.y;
        jb0 += 8; jb1 += 8;
        float2 np0 = *reinterpret_cast<const float2*>(lb + jb0);
        float2 np1 = *reinterpret_cast<const float2*>(lb + jb1);
        float n1 = ck1 + softmin3(r2s0, r1s0, r1s1);
        float n0 = ck0 + softmin3(dg0, up0, r1s0);
        p0c = np0; p1c = np1;
        r2s0 = r1s0; r2s1 = r1s1; r1s0 = n0; r1s1 = n1;
        sh_prev = up_in;
    };

    // Phase A: d = 1..127 (window [0,127])
    #pragma unroll 2
    for (int k = 0; k < 127; ++k) stepAC();

    // Phase B: 64 iters x 4 diags (d = 128..383), 2 rebirths per iter.
    // unroll 1: keep body I-cache resident (R9 lesson).
    #pragma unroll 1
    for (int q = 0; q < 64; ++q) {
        bool rb = (lane == q);
        // rebirth slot0 of lane q as row 2q+128
        r1s0 = rb ? BIGK : r1s0;  r2s0 = rb ? BIGK : r2s0;
        jb0  = rb ? (jb0 - 1024) : jb0;
        xv0  = rb ? px0 : xv0;
        p0c = *reinterpret_cast<const float2*>(lb + jb0);         // refresh
        stepB(); stepB();
        // rebirth slot1 of lane q as row 2q+129
        r1s1 = rb ? BIGK : r1s1;  r2s1 = rb ? BIGK : r2s1;
        jb1  = rb ? (jb1 - 1024) : jb1;
        xv1  = rb ? px1 : xv1;
        p1c = *reinterpret_cast<const float2*>(lb + jb1);         // refresh
        stepB(); stepB();
    }

    // Phase C: d = 384..510 (window [128,255])
    #pragma unroll 2
    for (int k = 0; k < 127; ++k) stepAC();

    // R[255,255]: row 255 at slot 127 -> lane 63, slot 1
    if (lane == 63) out[pair] = r1s1 * INVK;
}

extern "C" void kernel_launch(void* const* d_in, const int* in_sizes, int n_in,
                              void* d_out, int out_size, void* d_ws, size_t ws_size,
                              hipStream_t stream) {
    const float* x    = (const float*)d_in[0];   // [16,256]
    const float* y    = (const float*)d_in[1];   // [64,256]
    const float* bias = (const float*)d_in[2];   // [64,1]
    const float* wt   = (const float*)d_in[3];   // [64,256]
    float* out = (float*)d_out;                  // [16,64]
    dtw_kernel<<<Bn * On, 64, 0, stream>>>(x, y, bias, wt, out);
}